// Round 8
// baseline (46.637 us; speedup 1.0000x reference)
//
#include <hip/hip_runtime.h>
#include <hip/hip_bf16.h>
#include <stdint.h>

// Problem constants (fixed by reference)
#define BB 4
#define LL 256
#define WW 256
#define HH 768
#define NL 10
#define LT 16           // L-rows per block

typedef __attribute__((ext_vector_type(8))) short bf16x8;   // 8 bf16 (4 VGPRs)
typedef __attribute__((ext_vector_type(4))) float f32x4;    // MFMA C/D

__device__ inline unsigned short f2bf(float x) {            // RNE via HW cvt
    return __builtin_bit_cast(unsigned short, __float2bfloat16(x));
}
__device__ inline bf16x8 pack8(float4 a, float4 b) {
    union { bf16x8 v; unsigned short u[8]; } r;
    r.u[0] = f2bf(a.x); r.u[1] = f2bf(a.y); r.u[2] = f2bf(a.z); r.u[3] = f2bf(a.w);
    r.u[4] = f2bf(b.x); r.u[5] = f2bf(b.y); r.u[6] = f2bf(b.z); r.u[7] = f2bf(b.w);
    return r.v;
}

// ---------------------------------------------------------------------------
// ONE dispatch. Block = (b, 16 L-rows) covering ALL 256 W-cols -> the block is
// softmax-self-sufficient via the label-bucket trick (denominator = sum of its
// own 10 buckets; every w has exactly one label). 8 waves; each wave computes
// two 16x16 u-tiles (W-chunk = 32 cols), sharing one A-fragment per k-step.
// Then in-block: normalize buckets, 10-row epilogue + residual. No 2nd kernel.
// ---------------------------------------------------------------------------
__global__ __launch_bounds__(512, 1) void fused_kernel(
    const int* __restrict__ word_seq,           // [B,W]
    const float* __restrict__ hidden,           // [B,L,H]
    const int* __restrict__ label,              // [B,L,W]
    const float* __restrict__ mask,             // [B,L,W]
    const float* __restrict__ emb_a,            // [50000,H]
    const float* __restrict__ emb_c,            // [10,H]
    float* __restrict__ out)                    // [B,L,H]
{
    __shared__ float s_lds[LT][NL];
    __shared__ float inv[LT];

    const int t    = threadIdx.x;
    const int wv   = t >> 6, lane = t & 63;
    const int g    = lane >> 4, c = lane & 15;
    const int bid  = blockIdx.x;
    const int b    = bid >> 4, lt = bid & 15;
    const int l0   = lt * LT;

    if (t < LT * NL) ((float*)s_lds)[t] = 0.f;

    // ---- u-tiles: A row = lane&15 (M=l); B col = lane&15 (N=w) ----
    const int wcol0 = wv * 32 + c;
    const int wcol1 = wcol0 + 16;
    const int wr0 = word_seq[b * WW + wcol0];
    const int wr1 = word_seq[b * WW + wcol1];
    const float4* ap  = reinterpret_cast<const float4*>(
        hidden + ((size_t)(b * LL) + l0 + c) * HH + g * 8);   // 8 f4 per k-step
    const float4* bp0 = reinterpret_cast<const float4*>(
        emb_a + (size_t)wr0 * HH + g * 8);
    const float4* bp1 = reinterpret_cast<const float4*>(
        emb_a + (size_t)wr1 * HH + g * 8);

    // Depth-4 rotating prefetch (statically indexed after full unroll).
    float4 a0[4], a1[4], p0[4], p1[4], q0[4], q1[4];
    #pragma unroll
    for (int i = 0; i < 4; ++i) {
        a0[i] = ap[i * 8];  a1[i] = ap[i * 8 + 1];
        p0[i] = bp0[i * 8]; p1[i] = bp0[i * 8 + 1];
        q0[i] = bp1[i * 8]; q1[i] = bp1[i * 8 + 1];
    }

    f32x4 acc0 = {0.f, 0.f, 0.f, 0.f};
    f32x4 acc1 = {0.f, 0.f, 0.f, 0.f};
    #pragma unroll
    for (int k = 0; k < 24; ++k) {
        const int s = k & 3;
        bf16x8 av = pack8(a0[s], a1[s]);
        bf16x8 b0 = pack8(p0[s], p1[s]);
        bf16x8 b1 = pack8(q0[s], q1[s]);
        if (k + 4 < 24) {
            a0[s] = ap[(k + 4) * 8];  a1[s] = ap[(k + 4) * 8 + 1];
            p0[s] = bp0[(k + 4) * 8]; p1[s] = bp0[(k + 4) * 8 + 1];
            q0[s] = bp1[(k + 4) * 8]; q1[s] = bp1[(k + 4) * 8 + 1];
        }
        acc0 = __builtin_amdgcn_mfma_f32_16x16x32_bf16(av, b0, acc0, 0, 0, 0);
        acc1 = __builtin_amdgcn_mfma_f32_16x16x32_bf16(av, b1, acc1, 0, 0, 0);
    }
    __syncthreads();   // s_lds zeros visible to all waves

    // ---- masked exp + label buckets (C/D: col = lane&15, row = g*4+reg) ----
    const float scale = 0.03608439182435161f;  // 1/sqrt(768)
    #pragma unroll
    for (int r = 0; r < 4; ++r) {
        const int lrow = g * 4 + r;
        const size_t rowb = ((size_t)(b * LL) + l0 + lrow) * WW;
        {
            size_t idx = rowb + wcol0;
            float m = fminf(fmaxf(mask[idx], 0.f), 1.f);
            atomicAdd(&s_lds[lrow][label[idx]], __expf(acc0[r] * scale) * m);
        }
        {
            size_t idx = rowb + wcol1;
            float m = fminf(fmaxf(mask[idx], 0.f), 1.f);
            atomicAdd(&s_lds[lrow][label[idx]], __expf(acc1[r] * scale) * m);
        }
    }
    __syncthreads();

    // ---- normalize buckets in place ----
    if (t < LT) {
        float d = 1e-10f;
        #pragma unroll
        for (int k = 0; k < NL; ++k) d += s_lds[t][k];
        inv[t] = 1.f / d;
    }
    __syncthreads();
    if (t < LT * NL) ((float*)s_lds)[t] *= inv[t / NL];
    __syncthreads();

    // ---- epilogue: wave wv owns rows {2wv, 2wv+1}; float4 over H ----
    {
        const int r0 = wv * 2;
        float w0[NL], w1[NL];
        #pragma unroll
        for (int k = 0; k < NL; ++k) { w0[k] = s_lds[r0][k]; w1[k] = s_lds[r0 + 1][k]; }
        const float4* h4p = reinterpret_cast<const float4*>(hidden);
        const float4* ec4 = reinterpret_cast<const float4*>(emb_c);
        float4* o4 = reinterpret_cast<float4*>(out);
        const size_t rowA = (size_t)(b * LL) + l0 + r0;
        #pragma unroll
        for (int j = 0; j < 3; ++j) {
            const int h4 = j * 64 + lane;        // [0,192) float4 columns
            float4 s0 = h4p[rowA * 192 + h4];
            float4 s1 = h4p[(rowA + 1) * 192 + h4];
            #pragma unroll
            for (int k = 0; k < NL; ++k) {
                float4 e = ec4[k * 192 + h4];
                s0.x = fmaf(w0[k], e.x, s0.x); s0.y = fmaf(w0[k], e.y, s0.y);
                s0.z = fmaf(w0[k], e.z, s0.z); s0.w = fmaf(w0[k], e.w, s0.w);
                s1.x = fmaf(w1[k], e.x, s1.x); s1.y = fmaf(w1[k], e.y, s1.y);
                s1.z = fmaf(w1[k], e.z, s1.z); s1.w = fmaf(w1[k], e.w, s1.w);
            }
            o4[rowA * 192 + h4] = s0;
            o4[(rowA + 1) * 192 + h4] = s1;
        }
    }
}

extern "C" void kernel_launch(void* const* d_in, const int* in_sizes, int n_in,
                              void* d_out, int out_size, void* d_ws, size_t ws_size,
                              hipStream_t stream) {
    const int*   word_seq = (const int*)d_in[0];
    const float* hidden   = (const float*)d_in[1];
    const int*   label    = (const int*)d_in[2];
    const float* mask     = (const float*)d_in[3];
    const float* emb_a    = (const float*)d_in[4];
    const float* emb_c    = (const float*)d_in[5];
    float*       out      = (float*)d_out;

    fused_kernel<<<BB * LT, 512, 0, stream>>>(
        word_seq, hidden, label, mask, emb_a, emb_c, out);
}

// Round 9
// 16.950 us; speedup vs baseline: 2.7514x; 2.7514x over previous
//
#include <hip/hip_runtime.h>
#include <hip/hip_bf16.h>
#include <stdint.h>

// Problem constants (fixed by reference)
#define BB 4
#define LL 256
#define WW 256
#define HH 768
#define NL 10
#define LT 16           // L-rows per score block
#define WT 64           // W-cols per score block
#define ASTRIDE 776     // A_lds row stride in ushorts (97*8 -> 1552B, ~conflict-free)

typedef __attribute__((ext_vector_type(8))) short bf16x8;   // 8 bf16 (4 VGPRs)
typedef __attribute__((ext_vector_type(4))) float f32x4;    // MFMA C/D

__device__ inline unsigned short f2bf(float x) {            // RNE via HW cvt
    return __builtin_bit_cast(unsigned short, __float2bfloat16(x));
}
__device__ inline bf16x8 pack8(float4 a, float4 b) {
    union { bf16x8 v; unsigned short u[8]; } r;
    r.u[0] = f2bf(a.x); r.u[1] = f2bf(a.y); r.u[2] = f2bf(a.z); r.u[3] = f2bf(a.w);
    r.u[4] = f2bf(b.x); r.u[5] = f2bf(b.y); r.u[6] = f2bf(b.z); r.u[7] = f2bf(b.w);
    return r.v;
}

// ---------------------------------------------------------------------------
// K1: score. Block = (b, 16 L-rows, 64 W-cols); 4 waves, one 16x16 C-tile each.
//  - A (hidden rows) staged ONCE per block in LDS as bf16 (padded stride):
//    kills the 4x per-wave global re-read + 3/4 of cvt work.
//  - B (gathered emb_a rows) loaded direct fp32, depth-4 rotating prefetch.
//  - XCD swizzle: the 16 lt-blocks sharing (b,wt) -> same XCD, so the 384 KB
//    of shared B rows become L2-resident (blockIdx%8 round-robin heuristic).
// Writes UNNORMALIZED buckets s[16][10]; denominator D = sum_k s_k later.
// ---------------------------------------------------------------------------
__global__ __launch_bounds__(256, 1) void score_kernel(
    const int* __restrict__ word_seq,           // [B,W]
    const float* __restrict__ hidden,           // [B,L,H]
    const float* __restrict__ emb_a,            // [50000,H]
    const int* __restrict__ label,              // [B,L,W]
    const float* __restrict__ mask,             // [B,L,W]
    float* __restrict__ s_out)                  // [256 logical][16][10]
{
    __shared__ unsigned short A_lds[LT * ASTRIDE];   // 24832 B
    __shared__ float s_lds[LT][NL];

    const int t    = threadIdx.x;
    const int wave = t >> 6, lane = t & 63;
    const int g    = lane >> 4, c = lane & 15;

    // ---- XCD-grouped swizzle decode (bijective on [0,256)) ----
    // blockIdx = (G&7) + 8*(m + 16*(G>>3)),  G=(b*4+wt) in [0,16), m=lt.
    const int x    = blockIdx.x;
    const int G    = (x & 7) + 8 * (x >> 7);        // (x>>3)>>4 = x>>7
    const int lt   = (x >> 3) & 15;
    const int b    = G >> 2, wt = G & 3;
    const int l0   = lt * LT;

    if (t < LT * NL) ((float*)s_lds)[t] = 0.f;

    // ---- stage A: 16 rows x 768 fp32 -> bf16 LDS, 1536 8-elem units ----
    // idx = r*96 + u; consecutive t -> consecutive u (coalesced 32B reads).
    #pragma unroll
    for (int i = 0; i < 6; ++i) {
        int idx = t + i * 256;
        int r = idx / 96, u = idx - r * 96;
        const float4* src = reinterpret_cast<const float4*>(
            hidden + ((size_t)(b * LL) + l0 + r) * HH + u * 8);
        float4 v0 = src[0], v1 = src[1];
        *reinterpret_cast<bf16x8*>(&A_lds[r * ASTRIDE + u * 8]) = pack8(v0, v1);
    }

    // ---- B pointers: one gathered emb_a row per (wave,c) ----
    const int wcol = wt * WT + wave * 16 + c;
    const int wrow = word_seq[b * WW + wcol];
    const float4* bp = reinterpret_cast<const float4*>(
        emb_a + (size_t)wrow * HH + g * 8);      // 8 f4 per k-step

    // Depth-4 rotating prefetch for B (statically indexed after unroll).
    float4 rb0[4], rb1[4];
    #pragma unroll
    for (int i = 0; i < 4; ++i) { rb0[i] = bp[i * 8]; rb1[i] = bp[i * 8 + 1]; }

    __syncthreads();    // A_lds staged, s_lds zeroed

    f32x4 acc = {0.f, 0.f, 0.f, 0.f};
    #pragma unroll
    for (int k = 0; k < 24; ++k) {
        const int s = k & 3;
        bf16x8 bv = pack8(rb0[s], rb1[s]);
        bf16x8 av = *reinterpret_cast<const bf16x8*>(
            &A_lds[c * ASTRIDE + (4 * k + g) * 8]);
        if (k + 4 < 24) { rb0[s] = bp[(k + 4) * 8]; rb1[s] = bp[(k + 4) * 8 + 1]; }
        acc = __builtin_amdgcn_mfma_f32_16x16x32_bf16(av, bv, acc, 0, 0, 0);
    }

    // C/D layout (m89): col = lane&15 (w), row = (lane>>4)*4 + reg (l)
    const float scale = 0.03608439182435161f;  // 1/sqrt(768)
    #pragma unroll
    for (int r = 0; r < 4; ++r) {
        int lrow = g * 4 + r;
        size_t idx = ((size_t)(b * LL) + l0 + lrow) * WW + wcol;
        float m = mask[idx];
        m = fminf(fmaxf(m, 0.f), 1.f);
        float e = __expf(acc[r] * scale) * m;
        atomicAdd(&s_lds[lrow][label[idx]], e);
    }
    __syncthreads();

    // logical slot (b,lt,wt) so combine's indexing is unchanged
    if (t < LT * NL) {
        size_t sidx = ((size_t)((b * 16 + lt) * 4 + wt)) * (LT * NL) + t;
        s_out[sidx] = ((float*)s_lds)[t];
    }
}

// ---------------------------------------------------------------------------
// K2: combine W-tile partials, normalize, 10-row epilogue + residual.
// Block = (b, 16 L-rows, 192 h-cols); grid 256, 192 threads (3 waves).
// ---------------------------------------------------------------------------
__global__ __launch_bounds__(192, 4) void combine_kernel(
    const float* __restrict__ s_in,     // [256][16][10]
    const float* __restrict__ hidden,   // [B,L,H]
    const float* __restrict__ emb_c,    // [10,H]
    float* __restrict__ out)            // [B,L,H]
{
    __shared__ float sp[LT][NL];
    __shared__ float inv[LT];
    const int t = threadIdx.x;
    const int bid = blockIdx.x;
    const int hq = bid & 3, lt = (bid >> 2) & 15, b = bid >> 6;
    const int l0 = lt * LT;
    const int h = hq * 192 + t;

    if (t < LT * NL) {
        size_t base = ((size_t)(b * 16 + lt)) * 4 * (LT * NL);  // wt=0 slot
        float v = 0.f;
        #pragma unroll
        for (int wt = 0; wt < 4; ++wt) v += s_in[base + wt * (LT * NL) + t];
        ((float*)sp)[t] = v;
    }
    __syncthreads();
    if (t < LT) {
        float d = 1e-10f;
        #pragma unroll
        for (int k = 0; k < NL; ++k) d += sp[t][k];
        inv[t] = 1.f / d;
    }
    __syncthreads();

    float ec[NL];
    #pragma unroll
    for (int k = 0; k < NL; ++k) ec[k] = emb_c[k * HH + h];
    #pragma unroll
    for (int r = 0; r < LT; ++r) {
        size_t base = ((size_t)(b * LL) + l0 + r) * HH + h;
        float acc = 0.f;
        #pragma unroll
        for (int k = 0; k < NL; ++k) acc = fmaf(sp[r][k], ec[k], acc);
        out[base] = hidden[base] + acc * inv[r];
    }
}

extern "C" void kernel_launch(void* const* d_in, const int* in_sizes, int n_in,
                              void* d_out, int out_size, void* d_ws, size_t ws_size,
                              hipStream_t stream) {
    const int*   word_seq = (const int*)d_in[0];
    const float* hidden   = (const float*)d_in[1];
    const int*   label    = (const int*)d_in[2];
    const float* mask     = (const float*)d_in[3];
    const float* emb_a    = (const float*)d_in[4];
    const float* emb_c    = (const float*)d_in[5];
    float*       out      = (float*)d_out;

    float* s_out = (float*)d_ws;   // 256*160 fp32 = 160 KB scratch

    score_kernel<<<BB * 16 * 4, 256, 0, stream>>>(
        word_seq, hidden, emb_a, label, mask, s_out);
    combine_kernel<<<BB * 16 * 4, 192, 0, stream>>>(s_out, hidden, emb_c, out);
}